// Round 1
// baseline (70.320 us; speedup 1.0000x reference)
//
#include <hip/hip_runtime.h>
#include <math.h>

#define BB 4
#define RR 1024
#define NN 100
#define NROI (BB * RR)
#define RPB 2                      // ROIs per block: halves per-block latency, 2048 blocks => ~8/CU target
#define PPB (RPB * NN)             // 200 pairs per block -> Phase A is ONE iteration, no loop
#define NBLK (NROI / RPB)          // 2048 blocks

// packed best: high 32 = float bits of IoU (>=0, monotone), low 32 = ~gt_idx
// => atomicMax picks highest IoU; on exact tie, smallest gt index (argmax-first semantics).
#define INIT_PACK 0x00000000FFFFFFFFull

// corner i of a rect; sign conv. matches reference lxs=[.5,-.5,-.5,.5], lys=[.5,.5,-.5,-.5]
__device__ __forceinline__ void corner_of(int i, float cx0, float cy0, float dx, float dy,
                                          float c, float s, float& X, float& Y) {
    float sx = (i == 0 || i == 3) ? 0.5f : -0.5f;
    float sy = (i <= 1) ? 0.5f : -0.5f;
    float lx = sx * dx, ly = sy * dy;
    X = cx0 + lx * c - ly * s;
    Y = cy0 + lx * s + ly * c;
}

// Latency-bound kernel (see R0 theory): the whole grid is ~one residency round,
// so wall time ~= per-block critical path. This version cuts that path:
//  - NO LDS staging: gts (3.2KB/batch) is L1-resident; staging 800 floats + a
//    __syncthreads was pure serial overhead for RPB ROIs of reuse.
//  - RPB=2: Phase A is a single iteration; 2x blocks = 2x independent chains/CU.
//  - Phase A compaction via wave ballot (1 atomic per wave, not per hit).
//  - Phase B vertex ordering via branchless pseudo-angle copysign(1-x/(|x|+|y|), y):
//    strictly monotone in atan2(y,x) => identical cyclic order => identical area;
//    ties still broken by lane index. Kills the ~150cy dependent atan2f chain.
__global__ __launch_bounds__(256) void sampling_target_fused(
    const float* __restrict__ rois,   // (B,R,7)
    const int*   __restrict__ labels, // (B,R)
    const float* __restrict__ gts,    // (B,N,8)
    float*       __restrict__ out)
{
    __shared__ int   s_list[PPB];
    __shared__ int   s_cnt;
    __shared__ unsigned long long s_best[RPB];

    const int tid = threadIdx.x;
    const int roi0 = blockIdx.x * RPB;
    const int b = roi0 >> 10;                  // RR = 1024, RPB divides 1024 -> no batch straddle

    if (tid < RPB) s_best[tid] = INIT_PACK;
    if (tid == 0) s_cnt = 0;
    __syncthreads();

    // ---- Phase A: cheap reject + wave-ballot compaction (200 pairs, 1 iter) ----
    {
        bool hit = false;
        const int p = tid;
        if (p < PPB) {
            int rl = p / NN;
            int n = p - rl * NN;
            const float* A = &rois[(roi0 + rl) * 7];
            const float* G = &gts[(b * NN + n) * 8];
            float oh = fminf(A[2] + A[5] * 0.5f, G[2] + G[5] * 0.5f)
                     - fmaxf(A[2] - A[5] * 0.5f, G[2] - G[5] * 0.5f);
            float dxc = A[0] - G[0], dyc = A[1] - G[1];
            float ra = 0.5f * sqrtf(A[3] * A[3] + A[4] * A[4]);
            float rb = 0.5f * sqrtf(G[3] * G[3] + G[4] * G[4]);
            float rr = ra + rb;
            hit = (oh > 0.0f) && (dxc * dxc + dyc * dyc <= rr * rr);
        }
        unsigned long long m = __ballot(hit);
        int wl = tid & 63;
        int nh = __popcll(m);
        if (nh) {                               // wave-uniform
            int base = 0;
            if (wl == 0) base = atomicAdd(&s_cnt, nh);
            base = __shfl(base, 0, 64);
            if (hit) {
                int pfx = __popcll(m & ((1ull << wl) - 1ull));
                s_list[base + pfx] = p;        // capacity PPB: cannot overflow
            }
        }
    }
    __syncthreads();

    // ---- Phase B: lane-parallel exact IoU, one pair per 32-lane group ----
    const int cnt = s_cnt;                     // ~5 expected for RPB=2
    const int g = tid >> 5;                    // 8 groups per block
    const int lane = tid & 31;
    const int half = g & 1;

    for (int i = g; i < cnt; i += 8) {
        int p = s_list[i];
        int rl = p / NN;
        int n = p - rl * NN;
        const float* A = &rois[(roi0 + rl) * 7];   // group-uniform addr -> L1 broadcast
        const float* G = &gts[(b * NN + n) * 8];
        float ax = A[0], ay = A[1], az = A[2], adx = A[3], ady = A[4], adz = A[5], aang = A[6];
        float gx_ = G[0], gy_ = G[1], gz_ = G[2], gdx = G[3], gdy = G[4], gdz = G[5], gang = G[6];
        float acs = cosf(aang), asn = sinf(aang);
        float bcs = cosf(gang), bsn = sinf(gang);

        // my candidate vertex (lane -> reference slot k, same ordering)
        float ppx = 0.0f, ppy = 0.0f;
        bool val = false;
        if (lane < 4) {                        // corners of A, tested inside B
            corner_of(lane, ax, ay, adx, ady, acs, asn, ppx, ppy);
            float qx = ppx - gx_, qy = ppy - gy_;
            float lx = qx * bcs + qy * bsn;
            float ly = -qx * bsn + qy * bcs;
            val = (fabsf(lx) <= gdx * 0.5f + 1e-5f) && (fabsf(ly) <= gdy * 0.5f + 1e-5f);
        } else if (lane < 8) {                 // corners of B, tested inside A
            corner_of(lane - 4, gx_, gy_, gdx, gdy, bcs, bsn, ppx, ppy);
            float qx = ppx - ax, qy = ppy - ay;
            float lx = qx * acs + qy * asn;
            float ly = -qx * asn + qy * acs;
            val = (fabsf(lx) <= adx * 0.5f + 1e-5f) && (fabsf(ly) <= ady * 0.5f + 1e-5f);
        } else if (lane < 24) {                // edge i of A x edge j of B
            int e = lane - 8;
            int ii = e >> 2, jj = e & 3;
            float a1x, a1y, a2x, a2y, b1x, b1y, b2x, b2y;
            corner_of(ii, ax, ay, adx, ady, acs, asn, a1x, a1y);
            corner_of((ii + 1) & 3, ax, ay, adx, ady, acs, asn, a2x, a2y);
            corner_of(jj, gx_, gy_, gdx, gdy, bcs, bsn, b1x, b1y);
            corner_of((jj + 1) & 3, gx_, gy_, gdx, gdy, bcs, bsn, b2x, b2y);
            float d1x = a2x - a1x, d1y = a2y - a1y;
            float d2x = b2x - b1x, d2y = b2y - b1y;
            float denom = d1x * d2y - d1y * d2x;
            float fx = b1x - a1x, fy = b1y - a1y;
            float safe = (fabsf(denom) > 1e-8f) ? denom : 1e-8f;
            float t = (fx * d2y - fy * d2x) / safe;
            float u = (fx * d1y - fy * d1x) / safe;
            ppx = a1x + t * d1x;
            ppy = a1y + t * d1y;
            val = (fabsf(denom) > 1e-8f) && (t >= 0.0f) && (t <= 1.0f) && (u >= 0.0f) && (u <= 1.0f);
        }

        unsigned long long m = __ballot(val);
        unsigned gm = (unsigned)(half ? (m >> 32) : (m & 0xFFFFFFFFull));
        int nv = __popc(gm);

        float inter_bev = 0.0f;
        if (nv >= 3) {   // group-uniform branch; width-32 shuffles safe inside
            float sx = val ? ppx : 0.0f;
            float sy = val ? ppy : 0.0f;
#pragma unroll
            for (int off = 16; off; off >>= 1) {
                sx += __shfl_xor(sx, off, 32);
                sy += __shfl_xor(sy, off, 32);
            }
            float cx = sx / (float)nv, cy = sy / (float)nv;

            // pseudo-angle: strictly monotone in atan2(dyp,dxp) over (-pi,pi],
            // range (-2,2]. Identical cyclic order => identical shoelace area.
            float dxp = ppx - cx, dyp = ppy - cy;
            float den = fabsf(dxp) + fabsf(dyp);
            float pa = dxp / fmaxf(den, 1e-30f);
            float myAng = val ? copysignf(1.0f - pa, dyp) : 1e9f;

            // successor in (angle, index) order, index-only tracking;
            // ascending j + strict < reproduces stable-argsort tie rules.
            float sAng = 1e30f; int sIdx = 0; bool found = false;
            float gAng = 1e30f; int gIdx = 0;
#pragma unroll
            for (int j = 0; j < 24; j++) {
                float aj = __shfl(myAng, j, 32);
                if (aj < 1e8f) {   // valid j only
                    bool greater = (aj > myAng) || (aj == myAng && j > lane);
                    if (greater && aj < sAng) { sAng = aj; sIdx = j; found = true; }
                    if (aj < gAng) { gAng = aj; gIdx = j; }
                }
            }
            int qi = found ? sIdx : gIdx;
            float qx = __shfl(ppx, qi, 32);
            float qy = __shfl(ppy, qi, 32);
            float contrib = val ? (ppx * qy - qx * ppy) : 0.0f;
#pragma unroll
            for (int off = 16; off; off >>= 1)
                contrib += __shfl_xor(contrib, off, 32);
            inter_bev = 0.5f * fabsf(contrib);
        }

        if (lane == 0) {
            float oh = fminf(az + adz * 0.5f, gz_ + gdz * 0.5f)
                     - fmaxf(az - adz * 0.5f, gz_ - gdz * 0.5f);   // >0 by Phase A
            float inter = inter_bev * oh;
            float va = adx * ady * adz;
            float vb = gdx * gdy * gdz;
            float v = inter / fmaxf(va + vb - inter, 1e-6f);
            unsigned long long packed =
                ((unsigned long long)__float_as_uint(v) << 32) | (unsigned)(~(unsigned)n);
            atomicMax(&s_best[rl], packed);
        }
    }
    __syncthreads();

    // ---- Phase C: outputs (reads straight from global; gts/rois are L1-hot) ----
    if (tid < RPB) {
        int r = roi0 + tid;
        unsigned long long packed = s_best[tid];
        float mo = __uint_as_float((unsigned)(packed >> 32));
        int besti = (int)(~(unsigned)(packed & 0xFFFFFFFFu));   // no-survivor => 0 (matches argmax of zeros)

        const float* Ar = &rois[r * 7];
        const float* Gb = &gts[(b * NN + besti) * 8];

        float* out_rois = out;                    // NROI*7
        float* out_gor  = out + NROI * 7;         // NROI*8
        float* out_max  = out_gor + NROI * 8;     // NROI
        float* out_lab  = out_max + NROI;         // NROI
        float* out_msk  = out_lab + NROI;         // NROI

#pragma unroll
        for (int k = 0; k < 7; k++) out_rois[r * 7 + k] = Ar[k];
#pragma unroll
        for (int k = 0; k < 8; k++) out_gor[r * 8 + k] = Gb[k];
        out_max[r] = mo;
        out_lab[r] = (float)labels[r];
        out_msk[r] = (mo > 0.55f) ? 1.0f : 0.0f;
    }
}

extern "C" void kernel_launch(void* const* d_in, const int* in_sizes, int n_in,
                              void* d_out, int out_size, void* d_ws, size_t ws_size,
                              hipStream_t stream) {
    const float* rois   = (const float*)d_in[0];  // (4,1024,7) f32
    const int*   labels = (const int*)d_in[1];    // (4,1024) i32
    const float* gts    = (const float*)d_in[2];  // (4,100,8) f32
    float* out = (float*)d_out;

    hipLaunchKernelGGL(sampling_target_fused, dim3(NBLK), dim3(256), 0, stream,
                       rois, labels, gts, out);
}

// Round 2
// 66.260 us; speedup vs baseline: 1.0613x; 1.0613x over previous
//
#include <hip/hip_runtime.h>
#include <math.h>

#define BB 4
#define RR 1024
#define NN 100
#define NROI (BB * RR)
#define RPB 4                      // session-best grid shape: 1024 blocks, single residency round
#define PPB (RPB * NN)             // 400 pairs per block
#define NBLK (NROI / RPB)          // 1024 blocks

// packed best: high 32 = float bits of IoU (>=0, monotone), low 32 = ~gt_idx
// => atomicMax picks highest IoU; on exact tie, smallest gt index (argmax-first semantics).
#define INIT_PACK 0x00000000FFFFFFFFull

// corner i of a rect; sign conv. matches reference lxs=[.5,-.5,-.5,.5], lys=[.5,.5,-.5,-.5]
__device__ __forceinline__ void corner_of(int i, float cx0, float cy0, float dx, float dy,
                                          float c, float s, float& X, float& Y) {
    float sx = (i == 0 || i == 3) ? 0.5f : -0.5f;
    float sy = (i <= 1) ? 0.5f : -0.5f;
    float lx = sx * dx, ly = sy * dy;
    X = cx0 + lx * c - ly * s;
    Y = cy0 + lx * s + ly * c;
}

// R1: latency-bound kernel; wall time ~= per-block critical path (+ fixed 40us harness fill).
// Changes vs R0:
//  - RPB=4 / 1024 blocks: all blocks resident in ONE round (R0's 2048 blocks spilled
//    into a 2nd residency round -> tail).
//  - One-shot parallel staging computes cos/sin/enclosing-radius PER BOX (104 boxes,
//    104 threads, one transcendental round) -> Phase A is ~12 flops/pair with no
//    sqrt/trig; Phase B's dependent chain loses all 4 cosf/sinf (~300-400 cy).
//  - SoA LDS layout: conflict-free column reads in Phase A, broadcast reads in Phase B.
//  - Kept from R0: wave-ballot compaction (1 atomic/wave), branchless pseudo-angle
//    (monotone bijection of atan2 -> identical cyclic order -> identical area).
__global__ __launch_bounds__(256) void sampling_target_fused(
    const float* __restrict__ rois,   // (B,R,7)
    const int*   __restrict__ labels, // (B,R)
    const float* __restrict__ gts,    // (B,N,8)
    float*       __restrict__ out)
{
    __shared__ float s_gx[NN], s_gy[NN], s_gz[NN], s_gdx[NN], s_gdy[NN], s_gdz[NN],
                     s_gang[NN], s_glab[NN], s_gc[NN], s_gs[NN], s_grb[NN];
    __shared__ float s_rx[RPB], s_ry[RPB], s_rz[RPB], s_rdx[RPB], s_rdy[RPB], s_rdz[RPB],
                     s_rang[RPB], s_rc[RPB], s_rs[RPB], s_rra[RPB];
    __shared__ int   s_list[PPB];
    __shared__ int   s_cnt;
    __shared__ unsigned long long s_best[RPB];

    const int tid = threadIdx.x;
    const int roi0 = blockIdx.x * RPB;
    const int b = roi0 >> 10;                  // RR = 1024, RPB | 1024 -> no batch straddle

    // ---- stage: raw fields + derived (cos,sin,radius) per box, SoA ----
    if (tid < NN) {
        const float4* G = (const float4*)&gts[(b * NN + tid) * 8];   // 32B row -> 16B aligned
        float4 g0 = G[0];
        float4 g1 = G[1];
        s_gx[tid] = g0.x;  s_gy[tid] = g0.y;  s_gz[tid] = g0.z;  s_gdx[tid] = g0.w;
        s_gdy[tid] = g1.x; s_gdz[tid] = g1.y; s_gang[tid] = g1.z; s_glab[tid] = g1.w;
        s_gc[tid] = cosf(g1.z);
        s_gs[tid] = sinf(g1.z);
        s_grb[tid] = 0.5f * sqrtf(g0.w * g0.w + g1.x * g1.x);
    } else if (tid < NN + RPB) {
        int rl = tid - NN;
        const float* A = &rois[(roi0 + rl) * 7];
        float ax = A[0], ay = A[1], az = A[2], adx = A[3], ady = A[4], adz = A[5], aang = A[6];
        s_rx[rl] = ax; s_ry[rl] = ay; s_rz[rl] = az;
        s_rdx[rl] = adx; s_rdy[rl] = ady; s_rdz[rl] = adz; s_rang[rl] = aang;
        s_rc[rl] = cosf(aang);
        s_rs[rl] = sinf(aang);
        s_rra[rl] = 0.5f * sqrtf(adx * adx + ady * ady);
    }
    if (tid < RPB) s_best[tid] = INIT_PACK;
    if (tid == 0) s_cnt = 0;
    __syncthreads();

    // ---- Phase A: cheap reject (no trig/sqrt) + wave-ballot compaction ----
    for (int p0 = 0; p0 < PPB; p0 += 256) {    // fixed trip count: all lanes stay active
        int p = p0 + tid;
        bool hit = false;
        if (p < PPB) {
            int rl = p / NN;
            int n = p - rl * NN;
            float oh = fminf(s_rz[rl] + s_rdz[rl] * 0.5f, s_gz[n] + s_gdz[n] * 0.5f)
                     - fmaxf(s_rz[rl] - s_rdz[rl] * 0.5f, s_gz[n] - s_gdz[n] * 0.5f);
            float dxc = s_rx[rl] - s_gx[n], dyc = s_ry[rl] - s_gy[n];
            float rr = s_rra[rl] + s_grb[n];
            hit = (oh > 0.0f) && (dxc * dxc + dyc * dyc <= rr * rr);
        }
        unsigned long long m = __ballot(hit);
        int wl = tid & 63;
        int nh = __popcll(m);
        if (nh) {                               // wave-uniform
            int base = 0;
            if (wl == 0) base = atomicAdd(&s_cnt, nh);
            base = __shfl(base, 0, 64);
            if (hit) {
                int pfx = __popcll(m & ((1ull << wl) - 1ull));
                s_list[base + pfx] = p;        // capacity PPB: cannot overflow
            }
        }
    }
    __syncthreads();

    // ---- Phase B: lane-parallel exact IoU, one pair per 32-lane group ----
    const int cnt = s_cnt;                     // ~10 expected for RPB=4
    const int g = tid >> 5;                    // 8 groups per block
    const int lane = tid & 31;
    const int half = g & 1;

    for (int i = g; i < cnt; i += 8) {
        int p = s_list[i];
        int rl = p / NN;
        int n = p - rl * NN;
        // broadcast LDS reads (group-uniform addresses)
        float ax = s_rx[rl], ay = s_ry[rl], az = s_rz[rl];
        float adx = s_rdx[rl], ady = s_rdy[rl], adz = s_rdz[rl];
        float acs = s_rc[rl], asn = s_rs[rl];
        float gx_ = s_gx[n], gy_ = s_gy[n], gz_ = s_gz[n];
        float gdx = s_gdx[n], gdy = s_gdy[n], gdz = s_gdz[n];
        float bcs = s_gc[n], bsn = s_gs[n];

        // my candidate vertex (lane -> reference slot k, same ordering)
        float ppx = 0.0f, ppy = 0.0f;
        bool val = false;
        if (lane < 4) {                        // corners of A, tested inside B
            corner_of(lane, ax, ay, adx, ady, acs, asn, ppx, ppy);
            float qx = ppx - gx_, qy = ppy - gy_;
            float lx = qx * bcs + qy * bsn;
            float ly = -qx * bsn + qy * bcs;
            val = (fabsf(lx) <= gdx * 0.5f + 1e-5f) && (fabsf(ly) <= gdy * 0.5f + 1e-5f);
        } else if (lane < 8) {                 // corners of B, tested inside A
            corner_of(lane - 4, gx_, gy_, gdx, gdy, bcs, bsn, ppx, ppy);
            float qx = ppx - ax, qy = ppy - ay;
            float lx = qx * acs + qy * asn;
            float ly = -qx * asn + qy * acs;
            val = (fabsf(lx) <= adx * 0.5f + 1e-5f) && (fabsf(ly) <= ady * 0.5f + 1e-5f);
        } else if (lane < 24) {                // edge i of A x edge j of B
            int e = lane - 8;
            int ii = e >> 2, jj = e & 3;
            float a1x, a1y, a2x, a2y, b1x, b1y, b2x, b2y;
            corner_of(ii, ax, ay, adx, ady, acs, asn, a1x, a1y);
            corner_of((ii + 1) & 3, ax, ay, adx, ady, acs, asn, a2x, a2y);
            corner_of(jj, gx_, gy_, gdx, gdy, bcs, bsn, b1x, b1y);
            corner_of((jj + 1) & 3, gx_, gy_, gdx, gdy, bcs, bsn, b2x, b2y);
            float d1x = a2x - a1x, d1y = a2y - a1y;
            float d2x = b2x - b1x, d2y = b2y - b1y;
            float denom = d1x * d2y - d1y * d2x;
            float fx = b1x - a1x, fy = b1y - a1y;
            float safe = (fabsf(denom) > 1e-8f) ? denom : 1e-8f;
            float t = (fx * d2y - fy * d2x) / safe;
            float u = (fx * d1y - fy * d1x) / safe;
            ppx = a1x + t * d1x;
            ppy = a1y + t * d1y;
            val = (fabsf(denom) > 1e-8f) && (t >= 0.0f) && (t <= 1.0f) && (u >= 0.0f) && (u <= 1.0f);
        }

        unsigned long long m = __ballot(val);
        unsigned gm = (unsigned)(half ? (m >> 32) : (m & 0xFFFFFFFFull));
        int nv = __popc(gm);

        float inter_bev = 0.0f;
        if (nv >= 3) {   // group-uniform branch; width-32 shuffles safe inside
            float sx = val ? ppx : 0.0f;
            float sy = val ? ppy : 0.0f;
#pragma unroll
            for (int off = 16; off; off >>= 1) {
                sx += __shfl_xor(sx, off, 32);
                sy += __shfl_xor(sy, off, 32);
            }
            float cx = sx / (float)nv, cy = sy / (float)nv;

            // pseudo-angle: strictly monotone in atan2(dyp,dxp) over (-pi,pi],
            // range (-2,2]. Identical cyclic order => identical shoelace area.
            float dxp = ppx - cx, dyp = ppy - cy;
            float den = fabsf(dxp) + fabsf(dyp);
            float pa = dxp / fmaxf(den, 1e-30f);
            float myAng = val ? copysignf(1.0f - pa, dyp) : 1e9f;

            // successor in (angle, index) order, index-only tracking;
            // ascending j + strict < reproduces stable-argsort tie rules.
            float sAng = 1e30f; int sIdx = 0; bool found = false;
            float gAng = 1e30f; int gIdx = 0;
#pragma unroll
            for (int j = 0; j < 24; j++) {
                float aj = __shfl(myAng, j, 32);
                if (aj < 1e8f) {   // valid j only
                    bool greater = (aj > myAng) || (aj == myAng && j > lane);
                    if (greater && aj < sAng) { sAng = aj; sIdx = j; found = true; }
                    if (aj < gAng) { gAng = aj; gIdx = j; }
                }
            }
            int qi = found ? sIdx : gIdx;
            float qx = __shfl(ppx, qi, 32);
            float qy = __shfl(ppy, qi, 32);
            float contrib = val ? (ppx * qy - qx * ppy) : 0.0f;
#pragma unroll
            for (int off = 16; off; off >>= 1)
                contrib += __shfl_xor(contrib, off, 32);
            inter_bev = 0.5f * fabsf(contrib);
        }

        if (lane == 0) {
            float oh = fminf(az + adz * 0.5f, gz_ + gdz * 0.5f)
                     - fmaxf(az - adz * 0.5f, gz_ - gdz * 0.5f);   // >0 by Phase A
            float inter = inter_bev * oh;
            float va = adx * ady * adz;
            float vb = gdx * gdy * gdz;
            float v = inter / fmaxf(va + vb - inter, 1e-6f);
            unsigned long long packed =
                ((unsigned long long)__float_as_uint(v) << 32) | (unsigned)(~(unsigned)n);
            atomicMax(&s_best[rl], packed);
        }
    }
    __syncthreads();

    // ---- Phase C: outputs (all from LDS; labels from global, L1-hot) ----
    if (tid < RPB) {
        int r = roi0 + tid;
        unsigned long long packed = s_best[tid];
        float mo = __uint_as_float((unsigned)(packed >> 32));
        int besti = (int)(~(unsigned)(packed & 0xFFFFFFFFu));   // no-survivor => 0 (matches argmax of zeros)

        float* out_rois = out;                    // NROI*7
        float* out_gor  = out + NROI * 7;         // NROI*8
        float* out_max  = out_gor + NROI * 8;     // NROI
        float* out_lab  = out_max + NROI;         // NROI
        float* out_msk  = out_lab + NROI;         // NROI

        out_rois[r * 7 + 0] = s_rx[tid];
        out_rois[r * 7 + 1] = s_ry[tid];
        out_rois[r * 7 + 2] = s_rz[tid];
        out_rois[r * 7 + 3] = s_rdx[tid];
        out_rois[r * 7 + 4] = s_rdy[tid];
        out_rois[r * 7 + 5] = s_rdz[tid];
        out_rois[r * 7 + 6] = s_rang[tid];

        out_gor[r * 8 + 0] = s_gx[besti];
        out_gor[r * 8 + 1] = s_gy[besti];
        out_gor[r * 8 + 2] = s_gz[besti];
        out_gor[r * 8 + 3] = s_gdx[besti];
        out_gor[r * 8 + 4] = s_gdy[besti];
        out_gor[r * 8 + 5] = s_gdz[besti];
        out_gor[r * 8 + 6] = s_gang[besti];
        out_gor[r * 8 + 7] = s_glab[besti];

        out_max[r] = mo;
        out_lab[r] = (float)labels[r];
        out_msk[r] = (mo > 0.55f) ? 1.0f : 0.0f;
    }
}

extern "C" void kernel_launch(void* const* d_in, const int* in_sizes, int n_in,
                              void* d_out, int out_size, void* d_ws, size_t ws_size,
                              hipStream_t stream) {
    const float* rois   = (const float*)d_in[0];  // (4,1024,7) f32
    const int*   labels = (const int*)d_in[1];    // (4,1024) i32
    const float* gts    = (const float*)d_in[2];  // (4,100,8) f32
    float* out = (float*)d_out;

    hipLaunchKernelGGL(sampling_target_fused, dim3(NBLK), dim3(256), 0, stream,
                       rois, labels, gts, out);
}